// Round 4
// baseline (1328.300 us; speedup 1.0000x reference)
//
#include <hip/hip_runtime.h>
#include <math.h>

#define T_STEPS 16
#define NTOK 2048
#define WAVES_PER_BLOCK 8
#define BLOCK (WAVES_PER_BLOCK * 64)

// approx sqrt(q) = q * rsqrt_hack(q); rel err <= 3.42% (Lomont), full-rate only
__device__ __forceinline__ float approx_sqrt(float q) {
    float y = __uint_as_float(0x5f3759dfu - (__float_as_uint(q) >> 1));
    return q * y;
}

// X-macro over the 32 k-blocks: 32 NAMED scalar floats (always VGPRs; rule #20 —
// the R2 array version was demoted to scratch: 2.3 GB HBM traffic, 4x regression).
#define FOR_K(M) \
    M(0,da00)  M(1,da01)  M(2,da02)  M(3,da03)  M(4,da04)  M(5,da05)  M(6,da06)  M(7,da07) \
    M(8,da08)  M(9,da09)  M(10,da10) M(11,da11) M(12,da12) M(13,da13) M(14,da14) M(15,da15) \
    M(16,da16) M(17,da17) M(18,da18) M(19,da19) M(20,da20) M(21,da21) M(22,da22) M(23,da23) \
    M(24,da24) M(25,da25) M(26,da26) M(27,da27) M(28,da28) M(29,da29) M(30,da30) M(31,da31)

#define DECL_K(k, dk) float dk;

#define PASS1(k, dk) { \
    const float4 A  = ldsA[(k << 6) | lane]; \
    const float4 Bv = ldsB[(k << 6) | lane]; \
    float dx, dy; \
    dx = A.x  + u0x; dy = A.y  + u0y; const float q0 = fmaf(dy, dy, dx * dx); \
    dx = A.z  + u1x; dy = A.w  + u1y; const float q1 = fmaf(dy, dy, dx * dx); \
    dx = Bv.x + u2x; dy = Bv.y + u2y; const float q2 = fmaf(dy, dy, dx * dx); \
    dx = Bv.z + u3x; dy = Bv.w + u3y; const float q3 = fmaf(dy, dy, dx * dx); \
    dk = (approx_sqrt(q0) + approx_sqrt(q1)) + (approx_sqrt(q2) + approx_sqrt(q3)); \
    dmin = fminf(dmin, dk); }

#define PASS2(k, dk) if (__any(dk <= thr)) { \
    const int n = (k << 6) | lane; \
    const float4 A  = ldsA[n]; \
    const float4 Bv = ldsB[n]; \
    float dx, dy; \
    dx = A.x  + u0x; dy = A.y  + u0y; const float q0 = fmaf(dy, dy, dx * dx); \
    dx = A.z  + u1x; dy = A.w  + u1y; const float q1 = fmaf(dy, dy, dx * dx); \
    dx = Bv.x + u2x; dy = Bv.y + u2y; const float q2 = fmaf(dy, dy, dx * dx); \
    dx = Bv.z + u3x; dy = Bv.w + u3y; const float q3 = fmaf(dy, dy, dx * dx); \
    const float d = (__builtin_amdgcn_sqrtf(q0) + __builtin_amdgcn_sqrtf(q1)) + \
                    (__builtin_amdgcn_sqrtf(q2) + __builtin_amdgcn_sqrtf(q3)); \
    const bool upd = (d < bestd) || (d == bestd && n < bestn); \
    bestd = upd ? d : bestd; \
    bestn = upd ? n : bestn; }

__global__ __launch_bounds__(BLOCK, 4)
void tokenizer_kernel(const float* __restrict__ data,
                      const float* __restrict__ tok,
                      float* __restrict__ out,
                      int B) {
    __shared__ float4 ldsA[NTOK];   // corners 0,1: (x0,y0,x1,y1)
    __shared__ float4 ldsB[NTOK];   // corners 2,3: (x2,y2,x3,y3)

    const float4* src = (const float4*)tok;
    for (int j = threadIdx.x; j < 2 * NTOK; j += BLOCK) {
        float4 v = src[j];
        if (j & 1) ldsB[j >> 1] = v;
        else       ldsA[j >> 1] = v;
    }
    __syncthreads();

    const int wave = threadIdx.x >> 6;
    const int lane = threadIdx.x & 63;
    const int b = blockIdx.x * WAVES_PER_BLOCK + wave;
    if (b >= B) return;

    const float* db = data + (size_t)b * (T_STEPS * 3);
    float* outIdx  = out;
    float* outPos  = out + (size_t)B * T_STEPS;
    float* outHead = out + (size_t)B * T_STEPS * 3;

    float cpx = 0.f, cpy = 0.f;    // carry: prev_pos
    float rc = 1.f, rs = 0.f;      // carry: cos/sin(prev_head)

    for (int t = 0; t < T_STEPS; ++t) {
        const float px = db[t * 3 + 0];
        const float py = db[t * 3 + 1];
        const float hh = db[t * 3 + 2];

        // gt contour corners (lf, rf, rb, lb)
        float sh, ch;
        sincosf(hh, &sh, &ch);
        const float hc = 0.5f * ch, hs = 0.5f * sh;
        const float lc = 4.8f * hc, ls = 4.8f * hs;
        const float wc = 2.0f * hc, ws = 2.0f * hs;

        // e_j = cp - g_j ; u_j = R^T e_j  =>  dist_j = || f_j + u_j ||
        const float e0x = cpx - (px + lc - ws), e0y = cpy - (py + ls + wc);
        const float e1x = cpx - (px + lc + ws), e1y = cpy - (py + ls - wc);
        const float e2x = cpx - (px - lc + ws), e2y = cpy - (py - ls - wc);
        const float e3x = cpx - (px - lc - ws), e3y = cpy - (py - ls + wc);
        const float u0x = rc * e0x + rs * e0y, u0y = rc * e0y - rs * e0x;
        const float u1x = rc * e1x + rs * e1y, u1y = rc * e1y - rs * e1x;
        const float u2x = rc * e2x + rs * e2y, u2y = rc * e2y - rs * e2x;
        const float u3x = rc * e3x + rs * e3y, u3y = rc * e3y - rs * e3x;

        // ---- pass 1: approx distance for every token (no transcendentals)
        FOR_K(DECL_K)
        float dmin = 3.4e38f;
        FOR_K(PASS1)

        // wave-wide min of approx distance
        #pragma unroll
        for (int off = 32; off > 0; off >>= 1)
            dmin = fminf(dmin, __shfl_xor(dmin, off, 64));
        // threshold covers worst-case approx slack: 1.0342 <= 1.08 * 0.9658
        const float thr = dmin * 1.08f;

        // ---- pass 2: exact eval only for candidate blocks
        float bestd = 3.4e38f;
        int   bestn = 0;
        FOR_K(PASS2)

        // wave argmin reduction, lowest-index tie-break (matches jnp.argmin)
        #pragma unroll
        for (int off = 32; off > 0; off >>= 1) {
            const float od = __shfl_xor(bestd, off, 64);
            const int   on = __shfl_xor(bestn, off, 64);
            if (od < bestd || (od == bestd && on < bestn)) { bestd = od; bestn = on; }
        }

        // selected contour in global frame (same arithmetic as R1-passing version)
        const float4 A  = ldsA[bestn];
        const float4 Bv = ldsB[bestn];
        const float c0x = A.x  * rc - A.y  * rs + cpx, c0y = A.x  * rs + A.y  * rc + cpy;
        const float c1x = A.z  * rc - A.w  * rs + cpx, c1y = A.z  * rs + A.w  * rc + cpy;
        const float c2x = Bv.x * rc - Bv.y * rs + cpx, c2y = Bv.x * rs + Bv.y * rc + cpy;
        const float c3x = Bv.z * rc - Bv.w * rs + cpx, c3y = Bv.z * rs + Bv.w * rc + cpy;

        const float npx = 0.25f * (((c0x + c1x) + c2x) + c3x);
        const float npy = 0.25f * (((c0y + c1y) + c2y) + c3y);
        const float dxx = c0x - c3x, dyy = c0y - c3y;
        const float nh  = atan2f(dyy, dxx);

        if (lane == 0) {
            const int ot = b * T_STEPS + t;
            outIdx[ot]         = (float)bestn;
            outPos[2 * ot]     = npx;
            outPos[2 * ot + 1] = npy;
            outHead[ot]        = nh;
        }

        // carry: rotation directly from the contour edge (= cos/sin(atan2))
        cpx = npx; cpy = npy;
        const float len = __builtin_amdgcn_sqrtf(fmaf(dyy, dyy, dxx * dxx));
        rc = dxx / len;
        rs = dyy / len;
    }
}

extern "C" void kernel_launch(void* const* d_in, const int* in_sizes, int n_in,
                              void* d_out, int out_size, void* d_ws, size_t ws_size,
                              hipStream_t stream) {
    const float* data = (const float*)d_in[0];
    const float* tok  = (const float*)d_in[1];
    float* out = (float*)d_out;

    const int B = in_sizes[0] / (T_STEPS * 3);   // 4096
    const int grid = (B + WAVES_PER_BLOCK - 1) / WAVES_PER_BLOCK;

    tokenizer_kernel<<<grid, BLOCK, 0, stream>>>(data, tok, out, B);
}

// Round 5
// 657.606 us; speedup vs baseline: 2.0199x; 2.0199x over previous
//
#include <hip/hip_runtime.h>
#include <math.h>

#define T_STEPS 16
#define NTOK 2048
#define WAVES_PER_BLOCK 8
#define BLOCK (WAVES_PER_BLOCK * 64)

// approx sqrt(q) = q * rsqrt_hack(q); rel err <= 3.42% (Lomont), full-rate only
__device__ __forceinline__ float approx_sqrt(float q) {
    float y = __uint_as_float(0x5f3759dfu - (__float_as_uint(q) >> 1));
    return q * y;
}

// X-macro over the 32 k-blocks: 32 NAMED scalar floats (rule #20). The R2/R3
// spill was NOT the array per se: __launch_bounds__(512,4) imposed a 64-VGPR
// budget (4 blocks/CU * 8 waves = 8 waves/SIMD -> 512/8 = 64), forcing scratch.
// Fix: no min-occupancy arg; LDS already caps occupancy at 2 blocks/CU.
#define FOR_K(M) \
    M(0,da00)  M(1,da01)  M(2,da02)  M(3,da03)  M(4,da04)  M(5,da05)  M(6,da06)  M(7,da07) \
    M(8,da08)  M(9,da09)  M(10,da10) M(11,da11) M(12,da12) M(13,da13) M(14,da14) M(15,da15) \
    M(16,da16) M(17,da17) M(18,da18) M(19,da19) M(20,da20) M(21,da21) M(22,da22) M(23,da23) \
    M(24,da24) M(25,da25) M(26,da26) M(27,da27) M(28,da28) M(29,da29) M(30,da30) M(31,da31)

#define DECL_K(k, dk) float dk;

#define PASS1(k, dk) { \
    const float4 A  = ldsA[(k << 6) | lane]; \
    const float4 Bv = ldsB[(k << 6) | lane]; \
    float dx, dy; \
    dx = A.x  + u0x; dy = A.y  + u0y; const float q0 = fmaf(dy, dy, dx * dx); \
    dx = A.z  + u1x; dy = A.w  + u1y; const float q1 = fmaf(dy, dy, dx * dx); \
    dx = Bv.x + u2x; dy = Bv.y + u2y; const float q2 = fmaf(dy, dy, dx * dx); \
    dx = Bv.z + u3x; dy = Bv.w + u3y; const float q3 = fmaf(dy, dy, dx * dx); \
    dk = (approx_sqrt(q0) + approx_sqrt(q1)) + (approx_sqrt(q2) + approx_sqrt(q3)); \
    dmin = fminf(dmin, dk); }

#define PASS2(k, dk) if (__any(dk <= thr)) { \
    const int n = (k << 6) | lane; \
    const float4 A  = ldsA[n]; \
    const float4 Bv = ldsB[n]; \
    float dx, dy; \
    dx = A.x  + u0x; dy = A.y  + u0y; const float q0 = fmaf(dy, dy, dx * dx); \
    dx = A.z  + u1x; dy = A.w  + u1y; const float q1 = fmaf(dy, dy, dx * dx); \
    dx = Bv.x + u2x; dy = Bv.y + u2y; const float q2 = fmaf(dy, dy, dx * dx); \
    dx = Bv.z + u3x; dy = Bv.w + u3y; const float q3 = fmaf(dy, dy, dx * dx); \
    const float d = (__builtin_amdgcn_sqrtf(q0) + __builtin_amdgcn_sqrtf(q1)) + \
                    (__builtin_amdgcn_sqrtf(q2) + __builtin_amdgcn_sqrtf(q3)); \
    const bool upd = (d < bestd) || (d == bestd && n < bestn); \
    bestd = upd ? d : bestd; \
    bestn = upd ? n : bestn; }

__global__ __launch_bounds__(BLOCK)
void tokenizer_kernel(const float* __restrict__ data,
                      const float* __restrict__ tok,
                      float* __restrict__ out,
                      int B) {
    __shared__ float4 ldsA[NTOK];   // corners 0,1: (x0,y0,x1,y1)
    __shared__ float4 ldsB[NTOK];   // corners 2,3: (x2,y2,x3,y3)

    const float4* src = (const float4*)tok;
    for (int j = threadIdx.x; j < 2 * NTOK; j += BLOCK) {
        float4 v = src[j];
        if (j & 1) ldsB[j >> 1] = v;
        else       ldsA[j >> 1] = v;
    }
    __syncthreads();

    const int wave = threadIdx.x >> 6;
    const int lane = threadIdx.x & 63;
    const int b = blockIdx.x * WAVES_PER_BLOCK + wave;
    if (b >= B) return;

    const float* db = data + (size_t)b * (T_STEPS * 3);
    float* outIdx  = out;
    float* outPos  = out + (size_t)B * T_STEPS;
    float* outHead = out + (size_t)B * T_STEPS * 3;

    float cpx = 0.f, cpy = 0.f;    // carry: prev_pos
    float rc = 1.f, rs = 0.f;      // carry: cos/sin(prev_head)

    for (int t = 0; t < T_STEPS; ++t) {
        const float px = db[t * 3 + 0];
        const float py = db[t * 3 + 1];
        const float hh = db[t * 3 + 2];

        // gt contour corners (lf, rf, rb, lb)
        float sh, ch;
        sincosf(hh, &sh, &ch);
        const float hc = 0.5f * ch, hs = 0.5f * sh;
        const float lc = 4.8f * hc, ls = 4.8f * hs;
        const float wc = 2.0f * hc, ws = 2.0f * hs;

        // e_j = cp - g_j ; u_j = R^T e_j  =>  dist_j = || f_j + u_j ||
        const float e0x = cpx - (px + lc - ws), e0y = cpy - (py + ls + wc);
        const float e1x = cpx - (px + lc + ws), e1y = cpy - (py + ls - wc);
        const float e2x = cpx - (px - lc + ws), e2y = cpy - (py - ls - wc);
        const float e3x = cpx - (px - lc - ws), e3y = cpy - (py - ls + wc);
        const float u0x = rc * e0x + rs * e0y, u0y = rc * e0y - rs * e0x;
        const float u1x = rc * e1x + rs * e1y, u1y = rc * e1y - rs * e1x;
        const float u2x = rc * e2x + rs * e2y, u2y = rc * e2y - rs * e2x;
        const float u3x = rc * e3x + rs * e3y, u3y = rc * e3y - rs * e3x;

        // ---- pass 1: approx distance for every token (no transcendentals)
        FOR_K(DECL_K)
        float dmin = 3.4e38f;
        FOR_K(PASS1)

        // wave-wide min of approx distance
        #pragma unroll
        for (int off = 32; off > 0; off >>= 1)
            dmin = fminf(dmin, __shfl_xor(dmin, off, 64));
        // threshold covers worst-case approx slack: 1.0342 <= 1.08 * 0.9658
        const float thr = dmin * 1.08f;

        // ---- pass 2: exact eval only for candidate blocks
        float bestd = 3.4e38f;
        int   bestn = 0;
        FOR_K(PASS2)

        // wave argmin reduction, lowest-index tie-break (matches jnp.argmin)
        #pragma unroll
        for (int off = 32; off > 0; off >>= 1) {
            const float od = __shfl_xor(bestd, off, 64);
            const int   on = __shfl_xor(bestn, off, 64);
            if (od < bestd || (od == bestd && on < bestn)) { bestd = od; bestn = on; }
        }

        // selected contour in global frame (same arithmetic as R1-passing version)
        const float4 A  = ldsA[bestn];
        const float4 Bv = ldsB[bestn];
        const float c0x = A.x  * rc - A.y  * rs + cpx, c0y = A.x  * rs + A.y  * rc + cpy;
        const float c1x = A.z  * rc - A.w  * rs + cpx, c1y = A.z  * rs + A.w  * rc + cpy;
        const float c2x = Bv.x * rc - Bv.y * rs + cpx, c2y = Bv.x * rs + Bv.y * rc + cpy;
        const float c3x = Bv.z * rc - Bv.w * rs + cpx, c3y = Bv.z * rs + Bv.w * rc + cpy;

        const float npx = 0.25f * (((c0x + c1x) + c2x) + c3x);
        const float npy = 0.25f * (((c0y + c1y) + c2y) + c3y);
        const float dxx = c0x - c3x, dyy = c0y - c3y;
        const float nh  = atan2f(dyy, dxx);

        if (lane == 0) {
            const int ot = b * T_STEPS + t;
            outIdx[ot]         = (float)bestn;
            outPos[2 * ot]     = npx;
            outPos[2 * ot + 1] = npy;
            outHead[ot]        = nh;
        }

        // carry: rotation directly from the contour edge (= cos/sin(atan2))
        cpx = npx; cpy = npy;
        const float len = __builtin_amdgcn_sqrtf(fmaf(dyy, dyy, dxx * dxx));
        rc = dxx / len;
        rs = dyy / len;
    }
}

extern "C" void kernel_launch(void* const* d_in, const int* in_sizes, int n_in,
                              void* d_out, int out_size, void* d_ws, size_t ws_size,
                              hipStream_t stream) {
    const float* data = (const float*)d_in[0];
    const float* tok  = (const float*)d_in[1];
    float* out = (float*)d_out;

    const int B = in_sizes[0] / (T_STEPS * 3);   // 4096
    const int grid = (B + WAVES_PER_BLOCK - 1) / WAVES_PER_BLOCK;

    tokenizer_kernel<<<grid, BLOCK, 0, stream>>>(data, tok, out, B);
}

// Round 6
// 190.500 us; speedup vs baseline: 6.9727x; 3.4520x over previous
//
#include <hip/hip_runtime.h>
#include <hip/hip_fp16.h>
#include <math.h>

#define T_STEPS 16
#define NTOK 2048
#define WAVES_PER_BLOCK 8
#define BLOCK (WAVES_PER_BLOCK * 64)

typedef __fp16 half2_t __attribute__((ext_vector_type(2)));

// Quake approx: sqrt(q) ~= q * rsqrt_hack(q); rel err <= 3.42%, 3 full-rate ops
__device__ __forceinline__ float approx_sqrt(float q) {
    float y = __uint_as_float(0x5f3759dfu - (__float_as_uint(q) >> 1));
    return q * y;
}

// d~ for one 64-token block (lane's token in block k): ~30 full-rate VALU ops
#define DTILDE(k, dst) { \
    const float4 A  = ldsA[((k) << 6) | lane]; \
    const float4 Bv = ldsB[((k) << 6) | lane]; \
    float dx, dy; \
    dx = A.x  + u0x; dy = A.y  + u0y; const float q0 = fmaf(dy, dy, dx * dx); \
    dx = A.z  + u1x; dy = A.w  + u1y; const float q1 = fmaf(dy, dy, dx * dx); \
    dx = Bv.x + u2x; dy = Bv.y + u2y; const float q2 = fmaf(dy, dy, dx * dx); \
    dx = Bv.z + u3x; dy = Bv.w + u3y; const float q3 = fmaf(dy, dy, dx * dx); \
    dst = (approx_sqrt(q0) + approx_sqrt(q1)) + (approx_sqrt(q2) + approx_sqrt(q3)); }

// pass 1 pair: evaluate blocks 2j and 2j+1, pack the two d~ into one u32 (RTZ).
// sched_barrier(0) stops the scheduler hoisting all 64 ds_reads (R4's spill cause).
#define PASS1(j, pk) { \
    float da_, db_; \
    DTILDE(2*(j),   da_) \
    DTILDE(2*(j)+1, db_) \
    pk = __builtin_bit_cast(unsigned, __builtin_amdgcn_cvt_pkrtz(da_, db_)); \
    dmin = fminf(dmin, fminf(da_, db_)); \
    __builtin_amdgcn_sched_barrier(0); }

// exact eval of one 64-token block with v_sqrt; lexicographic (d, n) update
#define EXACT(k) { \
    const int n = ((k) << 6) | lane; \
    const float4 A  = ldsA[n]; \
    const float4 Bv = ldsB[n]; \
    float dx, dy; \
    dx = A.x  + u0x; dy = A.y  + u0y; const float q0 = fmaf(dy, dy, dx * dx); \
    dx = A.z  + u1x; dy = A.w  + u1y; const float q1 = fmaf(dy, dy, dx * dx); \
    dx = Bv.x + u2x; dy = Bv.y + u2y; const float q2 = fmaf(dy, dy, dx * dx); \
    dx = Bv.z + u3x; dy = Bv.w + u3y; const float q3 = fmaf(dy, dy, dx * dx); \
    const float d = (__builtin_amdgcn_sqrtf(q0) + __builtin_amdgcn_sqrtf(q1)) + \
                    (__builtin_amdgcn_sqrtf(q2) + __builtin_amdgcn_sqrtf(q3)); \
    const bool upd = (d < bestd) || (d == bestd && n < bestn); \
    bestd = upd ? d : bestd; \
    bestn = upd ? n : bestn; }

// pass 2: unpack the two stored f16 d~'s; exact-scan a block only if any lane fires
#define PASS2(j, pk) { \
    const half2_t h_ = __builtin_bit_cast(half2_t, pk); \
    if (__any((float)h_.x <= thr)) EXACT(2*(j)) \
    if (__any((float)h_.y <= thr)) EXACT(2*(j)+1) }

#define FOR_P(M) \
    M(0,pk00)  M(1,pk01)  M(2,pk02)  M(3,pk03)  M(4,pk04)  M(5,pk05)  M(6,pk06)  M(7,pk07) \
    M(8,pk08)  M(9,pk09)  M(10,pk10) M(11,pk11) M(12,pk12) M(13,pk13) M(14,pk14) M(15,pk15)

#define DECL_P(j, pk) unsigned pk;

__global__ __launch_bounds__(BLOCK)
void tokenizer_kernel(const float* __restrict__ data,
                      const float* __restrict__ tok,
                      float* __restrict__ out,
                      int B) {
    __shared__ float4 ldsA[NTOK];   // corners 0,1: (x0,y0,x1,y1)
    __shared__ float4 ldsB[NTOK];   // corners 2,3: (x2,y2,x3,y3)

    const float4* src = (const float4*)tok;
    for (int j = threadIdx.x; j < 2 * NTOK; j += BLOCK) {
        float4 v = src[j];
        if (j & 1) ldsB[j >> 1] = v;
        else       ldsA[j >> 1] = v;
    }
    __syncthreads();

    const int wave = threadIdx.x >> 6;
    const int lane = threadIdx.x & 63;
    const int b = blockIdx.x * WAVES_PER_BLOCK + wave;
    if (b >= B) return;

    const float* db = data + (size_t)b * (T_STEPS * 3);
    float* outIdx  = out;
    float* outPos  = out + (size_t)B * T_STEPS;
    float* outHead = out + (size_t)B * T_STEPS * 3;

    float cpx = 0.f, cpy = 0.f;    // carry: prev_pos
    float rc = 1.f, rs = 0.f;      // carry: cos/sin(prev_head)

    for (int t = 0; t < T_STEPS; ++t) {
        const float px = db[t * 3 + 0];
        const float py = db[t * 3 + 1];
        const float hh = db[t * 3 + 2];

        // gt contour corners (lf, rf, rb, lb)
        float sh, ch;
        sincosf(hh, &sh, &ch);
        const float hc = 0.5f * ch, hs = 0.5f * sh;
        const float lc = 4.8f * hc, ls = 4.8f * hs;
        const float wc = 2.0f * hc, ws = 2.0f * hs;

        // e_j = cp - g_j ; u_j = R^T e_j  =>  dist_j = || f_j + u_j ||
        const float e0x = cpx - (px + lc - ws), e0y = cpy - (py + ls + wc);
        const float e1x = cpx - (px + lc + ws), e1y = cpy - (py + ls - wc);
        const float e2x = cpx - (px - lc + ws), e2y = cpy - (py - ls - wc);
        const float e3x = cpx - (px - lc - ws), e3y = cpy - (py - ls + wc);
        const float u0x = rc * e0x + rs * e0y, u0y = rc * e0y - rs * e0x;
        const float u1x = rc * e1x + rs * e1y, u1y = rc * e1y - rs * e1x;
        const float u2x = rc * e2x + rs * e2y, u2y = rc * e2y - rs * e2x;
        const float u3x = rc * e3x + rs * e3y, u3y = rc * e3y - rs * e3x;

        // ---- pass 1: approx d~ for all tokens; 16 packed half2 in named VGPRs
        FOR_P(DECL_P)
        float dmin = 3.4e38f;
        FOR_P(PASS1)

        // wave-wide min of approx distance
        #pragma unroll
        for (int off = 32; off > 0; off >>= 1)
            dmin = fminf(dmin, __shfl_xor(dmin, off, 64));
        // sound threshold: 1.08*(1-0.0342) = 1.0431 >= (1+0.0342); RTZ pack only
        // shrinks stored d~, so the true argmin always passes the test.
        const float thr = dmin * 1.08f;

        // ---- pass 2: exact v_sqrt eval only for firing blocks
        float bestd = 3.4e38f;
        int   bestn = 0;
        FOR_P(PASS2)

        // wave argmin reduction, lowest-index tie-break (matches jnp.argmin)
        #pragma unroll
        for (int off = 32; off > 0; off >>= 1) {
            const float od = __shfl_xor(bestd, off, 64);
            const int   on = __shfl_xor(bestn, off, 64);
            if (od < bestd || (od == bestd && on < bestn)) { bestd = od; bestn = on; }
        }

        // selected contour in global frame (same arithmetic as R1-passing version)
        const float4 A  = ldsA[bestn];
        const float4 Bv = ldsB[bestn];
        const float c0x = A.x  * rc - A.y  * rs + cpx, c0y = A.x  * rs + A.y  * rc + cpy;
        const float c1x = A.z  * rc - A.w  * rs + cpx, c1y = A.z  * rs + A.w  * rc + cpy;
        const float c2x = Bv.x * rc - Bv.y * rs + cpx, c2y = Bv.x * rs + Bv.y * rc + cpy;
        const float c3x = Bv.z * rc - Bv.w * rs + cpx, c3y = Bv.z * rs + Bv.w * rc + cpy;

        const float npx = 0.25f * (((c0x + c1x) + c2x) + c3x);
        const float npy = 0.25f * (((c0y + c1y) + c2y) + c3y);
        const float dxx = c0x - c3x, dyy = c0y - c3y;
        const float nh  = atan2f(dyy, dxx);

        if (lane == 0) {
            const int ot = b * T_STEPS + t;
            outIdx[ot]         = (float)bestn;
            outPos[2 * ot]     = npx;
            outPos[2 * ot + 1] = npy;
            outHead[ot]        = nh;
        }

        // carry: rotation directly from the contour edge (= cos/sin(atan2))
        cpx = npx; cpy = npy;
        const float len = __builtin_amdgcn_sqrtf(fmaf(dyy, dyy, dxx * dxx));
        rc = dxx / len;
        rs = dyy / len;
    }
}

extern "C" void kernel_launch(void* const* d_in, const int* in_sizes, int n_in,
                              void* d_out, int out_size, void* d_ws, size_t ws_size,
                              hipStream_t stream) {
    const float* data = (const float*)d_in[0];
    const float* tok  = (const float*)d_in[1];
    float* out = (float*)d_out;

    const int B = in_sizes[0] / (T_STEPS * 3);   // 4096
    const int grid = (B + WAVES_PER_BLOCK - 1) / WAVES_PER_BLOCK;

    tokenizer_kernel<<<grid, BLOCK, 0, stream>>>(data, tok, out, B);
}